// Round 3
// baseline (951.767 us; speedup 1.0000x reference)
//
#include <hip/hip_runtime.h>
#include <cstdint>
#include <cstddef>

// Net: out = sign( BN_train( sign(x)@sign(W1)^T ) clipped ) @ sign(W4)^T
// B=8192, K=16384, H=384, O=10.  All values exact small integers.
//
// R3 structure:
//  - prep_x: streaming fp32 -> fp8(+-1,0) binarize of x (the 512MB read is
//    the pipeline's HBM floor; do it in a kernel that trivially hits BW).
//  - gemm1: NO LDS, NO barriers, NO in-loop packing. Per-lane direct loads
//    of fp8 A-fragments (x8 is L3-resident, 134MB) and register-resident W
//    fragments (L2-resident quarter). Waves fully independent -> latency
//    hidden by 16 waves/CU with compiler-scheduled vmcnt, no vmcnt(0) drain.
//  - split-K=4 with plain partial stores (no atomics); colstats fuses the
//    exact fp32 4-way reduce + BN stats.

typedef float v4f __attribute__((ext_vector_type(4)));
typedef long long v2l __attribute__((ext_vector_type(2)));

#define BATCH   8192
#define KDIM    16384
#define HID     384
#define OUT_F   10
#define BK      64
#define MT      32
#define SPLITK  4
#define KPB     (KDIM / SPLITK)      // 4096
#define NIT     (KPB / BK)           // 64
#define WCHUNK  (HID * BK)           // 24576 B fp8 W1 per BK-chunk

// ---- ws layout (bytes) ----
#define WS_W1C   0                         // 6,291,456
#define WS_X8    6291456                   // 134,217,728 (fp8 x)
#define WS_HP    140509184                 // 4 x 12,582,912 split-K partials
#define WS_H     190840832                 // 12,582,912 final h
#define WS_GSUM  203423744                 // double[384]
#define WS_GSQ   (WS_GSUM + 3072)
#define WS_MEAN  (WS_GSQ + 3072)
#define WS_COEF  (WS_MEAN + 3072)
#define WS_SW4   (WS_COEF + 3072)          // float[3840]

__device__ __forceinline__ uint32_t pack_sign4(v4f v) {
    uint32_t p = 0;
#pragma unroll
    for (int i = 0; i < 4; ++i) {
        uint32_t u = __float_as_uint(v[i]);
        // +1 -> 0x38, -1 -> 0xB8 (fp8 e4m3); exact +-0 -> 0 (matches jnp.sign)
        uint32_t b = ((u & 0x7fffffffu) == 0u) ? 0u : (0x38u | ((u >> 24) & 0x80u));
        p |= b << (8 * i);
    }
    return p;
}

// x fp32 -> fp8 sign, row-major. 16 floats/thread.
__global__ void prep_x(const float* __restrict__ x, uint8_t* __restrict__ x8) {
    size_t e = ((size_t)blockIdx.x * blockDim.x + threadIdx.x) * 16;
    uint4 p;
    p.x = pack_sign4(*(const v4f*)(x + e));
    p.y = pack_sign4(*(const v4f*)(x + e + 4));
    p.z = pack_sign4(*(const v4f*)(x + e + 8));
    p.w = pack_sign4(*(const v4f*)(x + e + 12));
    *(uint4*)(x8 + e) = p;
}

// W1 -> fp8, layout [it(256)][col(384)][q(4)][16B], 16B granule for (col,q) =
// k-bytes {q*8..+7} ++ {32+q*8..+7}: lane (q,l15) gets its whole B-fragment
// pair (s=0,1) in ONE dwordx4.  (verified exact in R1/R2)
__global__ void prep_w1(const float* __restrict__ W1, uint8_t* __restrict__ W1c) {
    size_t e = ((size_t)blockIdx.x * blockDim.x + threadIdx.x) * 4;
    int c   = (int)(e >> 14);
    int k   = (int)(e & 16383);
    int it  = k >> 6;
    int kin = k & 63;
    int s   = kin >> 5;
    int q   = (kin >> 3) & 3;
    int j   = kin & 7;
    v4f w = *(const v4f*)(W1 + e);
    uint32_t p = pack_sign4(w);
    *(uint32_t*)(W1c + (((size_t)it * HID + c) * 4 + q) * 16 + s * 8 + j) = p;
}

// Barrier-free binary GEMM. grid = (8192/32)*4 = 1024 blocks x 256 threads.
// Wave owns 96 cols (6 n-tiles) x 32 rows; W frags per-lane from L2,
// A frags per-lane dwordx2 from L3-resident x8.
__global__ __launch_bounds__(256, 4) void gemm1(const uint8_t* __restrict__ x8,
                                                const uint8_t* __restrict__ W1c,
                                                float* __restrict__ hpart) {
    const int t    = threadIdx.x;
    const int wave = t >> 6;
    const int lane = t & 63;
    const int q    = lane >> 4;
    const int l15  = lane & 15;
    const int kblk = blockIdx.x & (SPLITK - 1);
    const int m0   = (blockIdx.x >> 2) * MT;

    // A base: row (m0+l15), k = kblk*KPB + q*8;  mt stride 16 rows, s stride 32
    const uint8_t* xq = x8 + (size_t)(m0 + l15) * KDIM + (size_t)kblk * KPB + q * 8;
    // W base: lane (q,l15) col group; iter stride WCHUNK, nt stride 1024
    const uint8_t* wp = W1c + (size_t)kblk * ((size_t)NIT * WCHUNK)
                      + (((size_t)(wave * 96 + l15)) * 4 + q) * 16;

    v4f acc[2][6];
#pragma unroll
    for (int mt = 0; mt < 2; ++mt)
#pragma unroll
        for (int nt = 0; nt < 6; ++nt)
            acc[mt][nt] = v4f{0.f, 0.f, 0.f, 0.f};

    // A prologue (it=0): [mt][s]
    long long ac[2][2];
#pragma unroll
    for (int mt = 0; mt < 2; ++mt)
#pragma unroll
        for (int s = 0; s < 2; ++s)
            ac[mt][s] = *(const long long*)(xq + (size_t)mt * 16 * KDIM + s * 32);

#pragma unroll 2
    for (int it = 0; it < NIT; ++it) {
        // current-iter W fragments (L2-resident; used ~after A-next issue)
        v2l w[6];
        const uint8_t* wi = wp + (size_t)it * WCHUNK;
#pragma unroll
        for (int nt = 0; nt < 6; ++nt)
            w[nt] = *(const v2l*)(wi + nt * 1024);

        // next-iter A fragments (unconditional; last iter reads scratch, unused)
        long long an[2][2];
        const uint8_t* xi = xq + (size_t)(it + 1) * BK;
#pragma unroll
        for (int mt = 0; mt < 2; ++mt)
#pragma unroll
            for (int s = 0; s < 2; ++s)
                an[mt][s] = *(const long long*)(xi + (size_t)mt * 16 * KDIM + s * 32);

#pragma unroll
        for (int s = 0; s < 2; ++s)
#pragma unroll
            for (int nt = 0; nt < 6; ++nt)
#pragma unroll
                for (int mt = 0; mt < 2; ++mt)
                    acc[mt][nt] = __builtin_amdgcn_mfma_f32_16x16x32_fp8_fp8(
                        ac[mt][s], w[nt][s], acc[mt][nt], 0, 0, 0);

#pragma unroll
        for (int mt = 0; mt < 2; ++mt)
#pragma unroll
            for (int s = 0; s < 2; ++s)
                ac[mt][s] = an[mt][s];
    }

    // plain stores to this split's partial (C/D: col=l15, row=q*4+r) [m89]
    float* hp = hpart + (size_t)kblk * BATCH * HID;
#pragma unroll
    for (int nt = 0; nt < 6; ++nt) {
        const int col = wave * 96 + nt * 16 + l15;
#pragma unroll
        for (int mt = 0; mt < 2; ++mt)
#pragma unroll
            for (int r = 0; r < 4; ++r)
                hp[(size_t)(m0 + mt * 16 + q * 4 + r) * HID + col] = acc[mt][nt][r];
    }
}

// Reduce 4 split-K partials (exact fp32: int |p|<=4096) -> h, + BN stats.
__global__ void colstats(const float* __restrict__ hpart, float* __restrict__ h,
                         double* __restrict__ gsum, double* __restrict__ gsq) {
    int j  = threadIdx.x;          // 0..383
    int r0 = blockIdx.x * 32;
    double s = 0.0, sq = 0.0;
#pragma unroll 4
    for (int r = 0; r < 32; ++r) {
        size_t idx = (size_t)(r0 + r) * HID + j;
        float v = hpart[idx] + hpart[idx + (size_t)1 * BATCH * HID]
                + hpart[idx + (size_t)2 * BATCH * HID]
                + hpart[idx + (size_t)3 * BATCH * HID];
        h[idx] = v;
        double d = (double)v;
        s += d;
        sq += d * d;
    }
    atomicAdd(&gsum[j], s);
    atomicAdd(&gsq[j], sq);
}

__global__ void finalize(const double* __restrict__ gsum, const double* __restrict__ gsq,
                         const float* __restrict__ gamma, const float* __restrict__ W4,
                         double* __restrict__ meanArr, double* __restrict__ coefArr,
                         float* __restrict__ sW4) {
    int j = threadIdx.x;
    double mean = gsum[j] * (1.0 / (double)BATCH);
    double var  = gsq[j] * (1.0 / (double)BATCH) - mean * mean;
    meanArr[j] = mean;
    coefArr[j] = (double)gamma[j] / sqrt(var + 1e-5);
#pragma unroll
    for (int o = 0; o < OUT_F; ++o) {
        float w = W4[o * HID + j];
        sW4[o * HID + j] = (w > 0.f) ? 1.f : ((w < 0.f) ? -1.f : 0.f);
    }
}

// Per-row normalize -> sign -> 384x10 sign-GEMM. One wave per row.
__global__ __launch_bounds__(256) void head(const float* __restrict__ h,
                                            const double* __restrict__ meanArr,
                                            const double* __restrict__ coefArr,
                                            const float* __restrict__ beta,
                                            const float* __restrict__ sW4,
                                            float* __restrict__ out) {
    int wave = threadIdx.x >> 6;
    int lane = threadIdx.x & 63;
    int b = blockIdx.x * 4 + wave;
    float a[OUT_F];
#pragma unroll
    for (int o = 0; o < OUT_F; ++o) a[o] = 0.f;
#pragma unroll
    for (int i = 0; i < 6; ++i) {
        int j = lane + i * 64;
        double v = ((double)h[(size_t)b * HID + j] - meanArr[j]) * coefArr[j]
                 + (double)beta[j];
        float s = (v > 0.0) ? 1.f : ((v < 0.0) ? -1.f : 0.f);
#pragma unroll
        for (int o = 0; o < OUT_F; ++o) a[o] += s * sW4[o * HID + j];
    }
#pragma unroll
    for (int o = 0; o < OUT_F; ++o) {
#pragma unroll
        for (int off = 32; off > 0; off >>= 1) a[o] += __shfl_down(a[o], off);
    }
    if (lane == 0) {
#pragma unroll
        for (int o = 0; o < OUT_F; ++o) out[(size_t)b * OUT_F + o] = a[o];
    }
}

extern "C" void kernel_launch(void* const* d_in, const int* in_sizes, int n_in,
                              void* d_out, int out_size, void* d_ws, size_t ws_size,
                              hipStream_t stream) {
    const float* x     = (const float*)d_in[0];
    const float* W1    = (const float*)d_in[1];
    const float* gamma = (const float*)d_in[2];
    const float* beta  = (const float*)d_in[3];
    const float* W4    = (const float*)d_in[4];
    float* out = (float*)d_out;

    uint8_t* ws = (uint8_t*)d_ws;
    uint8_t* W1c     = ws + WS_W1C;
    uint8_t* x8      = ws + WS_X8;
    float*   hpart   = (float*)(ws + WS_HP);
    float*   h       = (float*)(ws + WS_H);
    double*  gsum    = (double*)(ws + WS_GSUM);
    double*  gsq     = (double*)(ws + WS_GSQ);
    double*  meanArr = (double*)(ws + WS_MEAN);
    double*  coefArr = (double*)(ws + WS_COEF);
    float*   sW4     = (float*)(ws + WS_SW4);

    prep_w1<<<6144, 256, 0, stream>>>(W1, W1c);
    prep_x<<<(BATCH * (size_t)KDIM) / 16 / 256, 256, 0, stream>>>(x, x8);
    hipMemsetAsync(gsum, 0, 2 * HID * sizeof(double), stream);
    gemm1<<<(BATCH / MT) * SPLITK, 256, 0, stream>>>(x8, W1c, hpart);
    colstats<<<BATCH / 32, HID, 0, stream>>>(hpart, h, gsum, gsq);
    finalize<<<1, HID, 0, stream>>>(gsum, gsq, gamma, W4, meanArr, coefArr, sW4);
    head<<<BATCH / 4, 256, 0, stream>>>(h, meanArr, coefArr, beta, sW4, out);
}